// Round 5
// baseline (760.845 us; speedup 1.0000x reference)
//
#include <hip/hip_runtime.h>

#define EPSV 1e-5f
#define BSH 8           // bucket shift: 256 nodes per bucket
#define BSZ 256
#define PCOLS 104       // stats partial spread columns

// bf16x2 helpers (bf16 = top 16 bits of fp32; element 2f = low half)
__device__ inline float blo(unsigned u) { return __uint_as_float(u << 16); }
__device__ inline float bhi(unsigned u) { return __uint_as_float(u & 0xFFFF0000u); }
__device__ inline unsigned rne16(float v) {
    unsigned u = __float_as_uint(v);
    return (u + 0x7FFFu + ((u >> 16) & 1u)) >> 16;
}
__device__ inline unsigned pk(float lo, float hi) {
    return (rne16(hi) << 16) | rne16(lo);
}

// ================= CSR build: multisplit, 256-node buckets, 4B pairs =====

__global__ __launch_bounds__(256) void k_hist(const int* __restrict__ dst,
                                              int* __restrict__ bcount, int E) {
    __shared__ int hist[1024];
    int t = threadIdx.x;
#pragma unroll
    for (int i = 0; i < 4; i++) hist[t + 256 * i] = 0;
    __syncthreads();
    int e0 = blockIdx.x * 4096;
#pragma unroll
    for (int r = 0; r < 16; r++) {
        int e = e0 + r * 256 + t;
        if (e < E) atomicAdd(&hist[dst[e] >> BSH], 1);
    }
    __syncthreads();
#pragma unroll
    for (int i = 0; i < 4; i++) {
        int bk = t + 256 * i;
        int h = hist[bk];
        if (h) atomicAdd(&bcount[bk], h);
    }
}

__global__ __launch_bounds__(256) void k_bscan(const int* __restrict__ bcount,
                                               int* __restrict__ bstart,
                                               int* __restrict__ gcur, int NB) {
    int t = threadIdx.x;
    int base = t * 4;
    int c[4], s = 0;
#pragma unroll
    for (int i = 0; i < 4; i++) {
        c[i] = (base + i < NB) ? bcount[base + i] : 0;
        s += c[i];
    }
    __shared__ int ls[256];
    ls[t] = s;
    __syncthreads();
    for (int off = 1; off < 256; off <<= 1) {
        int x = (t >= off) ? ls[t - off] : 0;
        __syncthreads();
        ls[t] += x;
        __syncthreads();
    }
    int run = (t == 0) ? 0 : ls[t - 1];
#pragma unroll
    for (int i = 0; i < 4; i++) {
        bstart[base + i] = run;
        gcur[base + i] = run;
        run += c[i];
    }
    if (t == 255) bstart[1024] = ls[255];
}

// pack: (dst_local << 22) | src   (src < 2^22, dst_local < 256)
__global__ __launch_bounds__(256) void k_split(const int* __restrict__ src,
                                               const int* __restrict__ dst,
                                               int* __restrict__ gcur,
                                               unsigned* __restrict__ pairs, int E) {
    __shared__ int hist[1024];   // reused as rank counters in pass 2
    __shared__ int gb[1024];
    int t = threadIdx.x;
    int e0 = blockIdx.x * 4096;
    int sreg[16], dreg[16];
#pragma unroll
    for (int i = 0; i < 4; i++) hist[t + 256 * i] = 0;
    __syncthreads();
#pragma unroll
    for (int r = 0; r < 16; r++) {
        int e = e0 + r * 256 + t;
        if (e < E) {
            sreg[r] = src[e];
            dreg[r] = dst[e];
            atomicAdd(&hist[dreg[r] >> BSH], 1);
        } else {
            dreg[r] = -1;
        }
    }
    __syncthreads();
#pragma unroll
    for (int i = 0; i < 4; i++) {
        int bk = t + 256 * i;
        int h = hist[bk];
        gb[bk] = h ? atomicAdd(&gcur[bk], h) : 0;
    }
    __syncthreads();
#pragma unroll
    for (int i = 0; i < 4; i++) hist[t + 256 * i] = 0;
    __syncthreads();
#pragma unroll
    for (int r = 0; r < 16; r++) {
        if (dreg[r] >= 0) {
            int bk = dreg[r] >> BSH;
            int rk = atomicAdd(&hist[bk], 1);
            pairs[gb[bk] + rk] = ((unsigned)(dreg[r] & (BSZ - 1)) << 22) |
                                 (unsigned)sreg[r];
        }
    }
}

// one block per 256-node bucket
__global__ __launch_bounds__(256) void k_build(const unsigned* __restrict__ pairs,
                                               const int* __restrict__ bstart,
                                               int* __restrict__ rowptr,
                                               int* __restrict__ rowend,
                                               float* __restrict__ dinv,
                                               int* __restrict__ colidx, int N) {
    int bid = blockIdx.x, t = threadIdx.x;
    int n0 = bid << BSH;
    int e0 = bstart[bid], e1 = bstart[bid + 1];
    __shared__ int cnt[256];
    __shared__ int ls[256];
    __shared__ int cur[256];
    cnt[t] = 0;
    __syncthreads();
    for (int e = e0 + t; e < e1; e += 256)
        atomicAdd(&cnt[pairs[e] >> 22], 1);
    __syncthreads();
    ls[t] = cnt[t];
    __syncthreads();
    for (int off = 1; off < 256; off <<= 1) {
        int x = (t >= off) ? ls[t - off] : 0;
        __syncthreads();
        ls[t] += x;
        __syncthreads();
    }
    int start = e0 + ((t == 0) ? 0 : ls[t - 1]);
    cur[t] = start;
    int node = n0 + t;
    if (node < N) {
        rowptr[node] = start;
        rowend[node] = start + cnt[t];
        dinv[node] = rsqrtf((float)cnt[t] + 1.0f);
    }
    __syncthreads();
    for (int e = e0 + t; e < e1; e += 256) {
        unsigned p = pairs[e];
        int r = atomicAdd(&cur[p >> 22], 1);
        colidx[r] = (int)(p & 0x3FFFFFu);
    }
}

// ================= network (bf16 hidden states) =================

// fused input + layer0: hl = bf16( dinv * (relu(x@Win+bin) @ W0) )
// wave per node; lane j owns output feature j; shuffle-broadcast of z.
__global__ __launch_bounds__(256) void k_gemm0(const float* __restrict__ x,
                                               const float* __restrict__ Win,
                                               const float* __restrict__ bin,
                                               const float* __restrict__ W,
                                               const float* __restrict__ dinv,
                                               unsigned short* __restrict__ hl, int N) {
    int j = threadIdx.x & 63;
    float w[64];
#pragma unroll
    for (int k = 0; k < 64; k++) w[k] = W[k * 64 + j];
    float wi[12];
#pragma unroll
    for (int k = 0; k < 12; k++) wi[k] = Win[k * 64 + j];
    float bj = bin[j];
    int wave = (blockIdx.x * 256 + threadIdx.x) >> 6;
    int nw = (gridDim.x * 256) >> 6;
    for (int node = wave; node < N; node += nw) {
        const float* xr = x + node * 12;
        float z = bj;
#pragma unroll
        for (int k = 0; k < 12; k++) z = fmaf(xr[k], wi[k], z);
        z = fmaxf(z, 0.0f);
        float acc = 0.0f;
#pragma unroll
        for (int k = 0; k < 64; k++) acc = fmaf(__shfl(z, k, 64), w[k], acc);
        hl[node * 64 + j] = (unsigned short)rne16(acc * dinv[node]);
    }
}

// fused BN-affine+relu + gemm (layers 1,2):
// hl = bf16( dinv * (relu(A*h+B) @ W) ), h read as raw bf16 agg output.
__global__ __launch_bounds__(256) void k_gemmn(const float* __restrict__ W,
                                               const float* __restrict__ ab,
                                               const float* __restrict__ dinv,
                                               const unsigned* __restrict__ h2,
                                               unsigned short* __restrict__ hl, int N) {
    int j = threadIdx.x & 63;
    float w[64];
#pragma unroll
    for (int k = 0; k < 64; k++) w[k] = W[k * 64 + j];
    float Aj = ab[j], Bj = ab[64 + j];
    int wave = (blockIdx.x * 256 + threadIdx.x) >> 6;
    int nw = (gridDim.x * 256) >> 6;
    for (int node = wave; node < N; node += nw) {
        unsigned u = h2[node * 32 + (j >> 1)];
        float h = (j & 1) ? bhi(u) : blo(u);
        float z = fmaxf(fmaf(Aj, h, Bj), 0.0f);
        float acc = 0.0f;
#pragma unroll
        for (int k = 0; k < 64; k++) acc = fmaf(__shfl(z, k, 64), w[k], acc);
        hl[node * 64 + j] = (unsigned short)rne16(acc * dinv[node]);
    }
}

// gather: out[d] = bf16( dinv[d]*(hl[d] + sum_s hl[s]) + b )
// half-wave per dst; 4 edge slots x 8 lanes x uint4; 16 edges in flight.
// Epilogue: per-block BN partial stats (fp32) -> spread atomicAdd into ps.
__global__ __launch_bounds__(256) void k_agg(const int* __restrict__ rowptr,
                                             const int* __restrict__ rowend,
                                             const int* __restrict__ colidx,
                                             const float* __restrict__ dinv,
                                             const unsigned* __restrict__ hl2,
                                             const float* __restrict__ b,
                                             unsigned* __restrict__ out2,
                                             float* __restrict__ ps, int N) {
    __shared__ float sm[8][64];
    int t = threadIdx.x;
    int hw = t >> 5;            // half-wave id: one dst row each
    int lane = t & 31;
    int sub = lane >> 3;        // edge slot 0..3
    int q = lane & 7;           // uint4 chunk within the 128B row
    int d = blockIdx.x * 8 + hw;
    bool valid = d < N;
    int dd = valid ? d : 0;
    int e0 = valid ? rowptr[dd] : 0;
    int e1 = valid ? rowend[dd] : 0;
    const uint4* H = (const uint4*)hl2;   // 8 x uint4 per 64-feat bf16 row

    float a0 = 0.f, a1 = 0.f, a2 = 0.f, a3 = 0.f;
    float a4 = 0.f, a5 = 0.f, a6 = 0.f, a7 = 0.f;
    float b0 = 0.f, b1 = 0.f, c0 = 0.f, c1 = 0.f;
    float g0 = 0.f, g1 = 0.f;
    float b2 = 0.f, b3 = 0.f, b4 = 0.f, b5 = 0.f, b6 = 0.f, b7 = 0.f;
    float c2 = 0.f, c3 = 0.f, c4 = 0.f, c5 = 0.f, c6 = 0.f, c7 = 0.f;
    float g2 = 0.f, g3 = 0.f, g4 = 0.f, g5 = 0.f, g6 = 0.f, g7 = 0.f;

    if (valid && sub == 0) {   // self-loop term, added once
        uint4 su = H[dd * 8 + q];
        a0 = blo(su.x); a1 = bhi(su.x);
        a2 = blo(su.y); a3 = bhi(su.y);
        a4 = blo(su.z); a5 = bhi(su.z);
        a6 = blo(su.w); a7 = bhi(su.w);
    }

    int e = e0 + sub;
    for (; e + 12 < e1; e += 16) {
        int s0 = colidx[e], s1 = colidx[e + 4];
        int s2 = colidx[e + 8], s3 = colidx[e + 12];
        uint4 u0 = H[s0 * 8 + q], u1 = H[s1 * 8 + q];
        uint4 u2 = H[s2 * 8 + q], u3 = H[s3 * 8 + q];
        a0 += blo(u0.x); a1 += bhi(u0.x); a2 += blo(u0.y); a3 += bhi(u0.y);
        a4 += blo(u0.z); a5 += bhi(u0.z); a6 += blo(u0.w); a7 += bhi(u0.w);
        b0 += blo(u1.x); b1 += bhi(u1.x); b2 += blo(u1.y); b3 += bhi(u1.y);
        b4 += blo(u1.z); b5 += bhi(u1.z); b6 += blo(u1.w); b7 += bhi(u1.w);
        c0 += blo(u2.x); c1 += bhi(u2.x); c2 += blo(u2.y); c3 += bhi(u2.y);
        c4 += blo(u2.z); c5 += bhi(u2.z); c6 += blo(u2.w); c7 += bhi(u2.w);
        g0 += blo(u3.x); g1 += bhi(u3.x); g2 += blo(u3.y); g3 += bhi(u3.y);
        g4 += blo(u3.z); g5 += bhi(u3.z); g6 += blo(u3.w); g7 += bhi(u3.w);
    }
    for (; e < e1; e += 4) {
        uint4 u = H[colidx[e] * 8 + q];
        a0 += blo(u.x); a1 += bhi(u.x); a2 += blo(u.y); a3 += bhi(u.y);
        a4 += blo(u.z); a5 += bhi(u.z); a6 += blo(u.w); a7 += bhi(u.w);
    }
    a0 += (b0 + c0) + g0; a1 += (b1 + c1) + g1;
    a2 += (b2 + c2) + g2; a3 += (b3 + c3) + g3;
    a4 += (b4 + c4) + g4; a5 += (b5 + c5) + g5;
    a6 += (b6 + c6) + g6; a7 += (b7 + c7) + g7;

    // butterfly across the 4 edge slots (stays inside the half-wave)
    a0 += __shfl_xor(a0, 8);  a0 += __shfl_xor(a0, 16);
    a1 += __shfl_xor(a1, 8);  a1 += __shfl_xor(a1, 16);
    a2 += __shfl_xor(a2, 8);  a2 += __shfl_xor(a2, 16);
    a3 += __shfl_xor(a3, 8);  a3 += __shfl_xor(a3, 16);
    a4 += __shfl_xor(a4, 8);  a4 += __shfl_xor(a4, 16);
    a5 += __shfl_xor(a5, 8);  a5 += __shfl_xor(a5, 16);
    a6 += __shfl_xor(a6, 8);  a6 += __shfl_xor(a6, 16);
    a7 += __shfl_xor(a7, 8);  a7 += __shfl_xor(a7, 16);

    if (sub == 0) {
        float dv = dinv[dd];
        int fb = q * 8;
        float o0 = fmaf(a0, dv, b[fb + 0]);
        float o1 = fmaf(a1, dv, b[fb + 1]);
        float o2 = fmaf(a2, dv, b[fb + 2]);
        float o3 = fmaf(a3, dv, b[fb + 3]);
        float o4 = fmaf(a4, dv, b[fb + 4]);
        float o5 = fmaf(a5, dv, b[fb + 5]);
        float o6 = fmaf(a6, dv, b[fb + 6]);
        float o7 = fmaf(a7, dv, b[fb + 7]);
        if (valid) {
            uint4 o;
            o.x = pk(o0, o1);
            o.y = pk(o2, o3);
            o.z = pk(o4, o5);
            o.w = pk(o6, o7);
            ((uint4*)out2)[dd * 8 + q] = o;
        }
        float zz = valid ? 1.0f : 0.0f;
        sm[hw][fb + 0] = o0 * zz; sm[hw][fb + 1] = o1 * zz;
        sm[hw][fb + 2] = o2 * zz; sm[hw][fb + 3] = o3 * zz;
        sm[hw][fb + 4] = o4 * zz; sm[hw][fb + 5] = o5 * zz;
        sm[hw][fb + 6] = o6 * zz; sm[hw][fb + 7] = o7 * zz;
    }
    __syncthreads();
    if (t < 64) {
        float s = 0.f, qq = 0.f;
#pragma unroll
        for (int h = 0; h < 8; h++) {
            float v = sm[h][t];
            s += v; qq = fmaf(v, v, qq);
        }
        int col = blockIdx.x % PCOLS;
        atomicAdd(&ps[t * PCOLS + col], s);
        atomicAdd(&ps[(64 + t) * PCOLS + col], qq);
    }
}

// reduce spread partials -> BN affine A,B (ab[0..63]=A, ab[64..127]=B)
__global__ __launch_bounds__(64) void k_red(const float* __restrict__ ps,
                                            const float* __restrict__ gamma,
                                            const float* __restrict__ beta,
                                            float* __restrict__ ab, float invN) {
    int t = threadIdx.x;   // 64 threads, one per feature
    float S = 0.f, Q = 0.f;
    for (int i = 0; i < PCOLS; i++) {
        S += ps[t * PCOLS + i];
        Q += ps[(64 + t) * PCOLS + i];
    }
    float mu = S * invN;
    float var = fmaf(-mu, mu, Q * invN);
    float A = rsqrtf(var + EPSV) * gamma[t];
    ab[t] = A;
    ab[64 + t] = fmaf(-mu, A, beta[t]);
}

// classifier with BN2 affine folded into W1/b1 (no relu after BN2)
__global__ __launch_bounds__(256) void k_cls(const unsigned* __restrict__ h2,
                                             const float* __restrict__ ab,
                                             const float* __restrict__ W1,
                                             const float* __restrict__ b1,
                                             const float* __restrict__ W2,
                                             const float* __restrict__ b2,
                                             float* __restrict__ out, int N) {
    int lane = threadIdx.x & 63;
    int half = lane >> 5, jj = lane & 31;
    float w[64];
    float bj = b1[jj];
#pragma unroll
    for (int k = 0; k < 64; k++) {
        float w1 = W1[k * 32 + jj];
        w[k] = ab[k] * w1;
        bj = fmaf(ab[64 + k], w1, bj);
    }
    float w20 = W2[jj * 2 + 0], w21 = W2[jj * 2 + 1];
    float b20 = b2[0], b21 = b2[1];
    int wave = (blockIdx.x * 256 + threadIdx.x) >> 6;
    int nw = (gridDim.x * 256) >> 6;
    for (int base = wave * 2; base < N; base += nw * 2) {
        int node = base + half;
        int vnode = node < N ? node : 0;
        const uint4* row = (const uint4*)(h2 + vnode * 32);
        float acc = bj;
#pragma unroll
        for (int kk = 0; kk < 8; kk++) {
            uint4 u = row[kk];
            acc = fmaf(blo(u.x), w[8 * kk + 0], acc);
            acc = fmaf(bhi(u.x), w[8 * kk + 1], acc);
            acc = fmaf(blo(u.y), w[8 * kk + 2], acc);
            acc = fmaf(bhi(u.y), w[8 * kk + 3], acc);
            acc = fmaf(blo(u.z), w[8 * kk + 4], acc);
            acc = fmaf(bhi(u.z), w[8 * kk + 5], acc);
            acc = fmaf(blo(u.w), w[8 * kk + 6], acc);
            acc = fmaf(bhi(u.w), w[8 * kk + 7], acc);
        }
        float hv = fmaxf(acc, 0.0f);
        float t0 = hv * w20, t1 = hv * w21;
#pragma unroll
        for (int m = 1; m <= 16; m <<= 1) {
            t0 += __shfl_xor(t0, m, 64);
            t1 += __shfl_xor(t1, m, 64);
        }
        if (jj == 0 && node < N) {
            ((float2*)out)[node] = make_float2(t0 + b20, t1 + b21);
        }
    }
}

extern "C" void kernel_launch(void* const* d_in, const int* in_sizes, int n_in,
                              void* d_out, int out_size, void* d_ws, size_t ws_size,
                              hipStream_t stream) {
    const float* x     = (const float*)d_in[0];
    const int*   ei    = (const int*)d_in[1];
    const float* Win   = (const float*)d_in[2];
    const float* bin   = (const float*)d_in[3];
    const float* Wg    = (const float*)d_in[4];
    const float* bg    = (const float*)d_in[5];
    const float* gamma = (const float*)d_in[6];
    const float* beta  = (const float*)d_in[7];
    const float* W1    = (const float*)d_in[8];
    const float* b1    = (const float*)d_in[9];
    const float* W2    = (const float*)d_in[10];
    const float* b2    = (const float*)d_in[11];
    float* out = (float*)d_out;

    int N = in_sizes[0] / 12;
    int E = in_sizes[1] / 2;
    const int* src = ei;
    const int* dst = ei + E;
    float invN = 1.0f / (float)N;
    int NB = (N + BSZ - 1) >> BSH;

    char* ws = (char*)d_ws;
    size_t szhin = ((size_t)N * 64 * 2 + 255) / 256 * 256;  // bf16 hidden
    size_t szE4  = ((size_t)E * 4 + 255) / 256 * 256;
    size_t szN4  = ((size_t)N * 4 + 255) / 256 * 256;
    size_t szps  = (size_t)128 * PCOLS * 4;                 // one layer's partials

    size_t off = 0;
    unsigned* hin2     = (unsigned*)(ws + off); off += szhin;
    unsigned short* hl = (unsigned short*)(ws + off); off += szhin;
    int* colidx        = (int*)(ws + off); off += szE4;
    int* rowptr        = (int*)(ws + off); off += szN4;
    int* rowend        = (int*)(ws + off); off += szN4;
    float* dinv        = (float*)(ws + off); off += szN4;
    int* bcount        = (int*)(ws + off); off += 4096;     // memset start
    float* ps          = (float*)(ws + off); off += 3 * szps;
    size_t msz = 4096 + 3 * szps;                           // bcount + ps, one memset
    int* bstart        = (int*)(ws + off); off += 8192;     // 1025 ints
    int* gcur          = (int*)(ws + off); off += 4096;
    float* ab          = (float*)(ws + off); off += 512;

    // packed pairs (4B) alias [hin2 | hl] — consumed by k_build before k_gemm0
    unsigned* pairs = (unsigned*)ws;
    size_t need = off;
    if (2 * szhin < (size_t)E * 4) {
        pairs = (unsigned*)(ws + off);
        need += (size_t)E * 4;
    }
    if (ws_size < need || NB > 1024 || N >= (1 << 22)) return;  // loud failure

    hipMemsetAsync(bcount, 0, msz, stream);

    int EB = (E + 4095) / 4096;
    k_hist<<<EB, 256, 0, stream>>>(dst, bcount, E);
    k_bscan<<<1, 256, 0, stream>>>(bcount, bstart, gcur, NB);
    k_split<<<EB, 256, 0, stream>>>(src, dst, gcur, pairs, E);
    k_build<<<NB, 256, 0, stream>>>(pairs, bstart, rowptr, rowend, dinv, colidx, N);

    int AB = (N + 7) / 8;
    for (int i = 0; i < 3; i++) {
        if (i == 0)
            k_gemm0<<<1024, 256, 0, stream>>>(x, Win, bin, Wg, dinv, hl, N);
        else
            k_gemmn<<<1024, 256, 0, stream>>>(Wg + i * 64 * 64, ab, dinv, hin2,
                                              hl, N);
        k_agg<<<AB, 256, 0, stream>>>(rowptr, rowend, colidx, dinv,
                                      (const unsigned*)hl, bg + i * 64, hin2,
                                      ps + (size_t)i * 128 * PCOLS, N);
        k_red<<<1, 64, 0, stream>>>(ps + (size_t)i * 128 * PCOLS, gamma + i * 64,
                                    beta + i * 64, ab, invN);
    }
    k_cls<<<1024, 256, 0, stream>>>(hin2, ab, W1, b1, W2, b2, out, N);
}

// Round 6
// 644.675 us; speedup vs baseline: 1.1802x; 1.1802x over previous
//
#include <hip/hip_runtime.h>

#define EPSV 1e-5f
#define BSH 8           // bucket shift: 256 nodes per bucket
#define BSZ 256
#define PCOLS 104       // stats partial spread columns

// bf16x2 helpers (bf16 = top 16 bits of fp32; element 2f = low half)
__device__ inline float blo(unsigned u) { return __uint_as_float(u << 16); }
__device__ inline float bhi(unsigned u) { return __uint_as_float(u & 0xFFFF0000u); }
__device__ inline unsigned rne16(float v) {
    unsigned u = __float_as_uint(v);
    return (u + 0x7FFFu + ((u >> 16) & 1u)) >> 16;
}
__device__ inline unsigned pk(float lo, float hi) {
    return (rne16(hi) << 16) | rne16(lo);
}

// ================= CSR build: multisplit, 256-node buckets, 4B pairs =====

__global__ __launch_bounds__(256) void k_hist(const int* __restrict__ dst,
                                              int* __restrict__ bcount, int E) {
    __shared__ int hist[1024];
    int t = threadIdx.x;
#pragma unroll
    for (int i = 0; i < 4; i++) hist[t + 256 * i] = 0;
    __syncthreads();
    int e0 = blockIdx.x * 4096;
#pragma unroll
    for (int r = 0; r < 16; r++) {
        int e = e0 + r * 256 + t;
        if (e < E) atomicAdd(&hist[dst[e] >> BSH], 1);
    }
    __syncthreads();
#pragma unroll
    for (int i = 0; i < 4; i++) {
        int bk = t + 256 * i;
        int h = hist[bk];
        if (h) atomicAdd(&bcount[bk], h);
    }
}

__global__ __launch_bounds__(256) void k_bscan(const int* __restrict__ bcount,
                                               int* __restrict__ bstart,
                                               int* __restrict__ gcur, int NB) {
    int t = threadIdx.x;
    int base = t * 4;
    int c[4], s = 0;
#pragma unroll
    for (int i = 0; i < 4; i++) {
        c[i] = (base + i < NB) ? bcount[base + i] : 0;
        s += c[i];
    }
    __shared__ int ls[256];
    ls[t] = s;
    __syncthreads();
    for (int off = 1; off < 256; off <<= 1) {
        int x = (t >= off) ? ls[t - off] : 0;
        __syncthreads();
        ls[t] += x;
        __syncthreads();
    }
    int run = (t == 0) ? 0 : ls[t - 1];
#pragma unroll
    for (int i = 0; i < 4; i++) {
        bstart[base + i] = run;
        gcur[base + i] = run;
        run += c[i];
    }
    if (t == 255) bstart[1024] = ls[255];
}

// pack: (dst_local << 22) | src   (src < 2^22, dst_local < 256)
__global__ __launch_bounds__(256) void k_split(const int* __restrict__ src,
                                               const int* __restrict__ dst,
                                               int* __restrict__ gcur,
                                               unsigned* __restrict__ pairs, int E) {
    __shared__ int hist[1024];   // reused as rank counters in pass 2
    __shared__ int gb[1024];
    int t = threadIdx.x;
    int e0 = blockIdx.x * 4096;
    int sreg[16], dreg[16];
#pragma unroll
    for (int i = 0; i < 4; i++) hist[t + 256 * i] = 0;
    __syncthreads();
#pragma unroll
    for (int r = 0; r < 16; r++) {
        int e = e0 + r * 256 + t;
        if (e < E) {
            sreg[r] = src[e];
            dreg[r] = dst[e];
            atomicAdd(&hist[dreg[r] >> BSH], 1);
        } else {
            dreg[r] = -1;
        }
    }
    __syncthreads();
#pragma unroll
    for (int i = 0; i < 4; i++) {
        int bk = t + 256 * i;
        int h = hist[bk];
        gb[bk] = h ? atomicAdd(&gcur[bk], h) : 0;
    }
    __syncthreads();
#pragma unroll
    for (int i = 0; i < 4; i++) hist[t + 256 * i] = 0;
    __syncthreads();
#pragma unroll
    for (int r = 0; r < 16; r++) {
        if (dreg[r] >= 0) {
            int bk = dreg[r] >> BSH;
            int rk = atomicAdd(&hist[bk], 1);
            pairs[gb[bk] + rk] = ((unsigned)(dreg[r] & (BSZ - 1)) << 22) |
                                 (unsigned)sreg[r];
        }
    }
}

// one block per 256-node bucket
__global__ __launch_bounds__(256) void k_build(const unsigned* __restrict__ pairs,
                                               const int* __restrict__ bstart,
                                               int* __restrict__ rowptr,
                                               int* __restrict__ rowend,
                                               float* __restrict__ dinv,
                                               int* __restrict__ colidx, int N) {
    int bid = blockIdx.x, t = threadIdx.x;
    int n0 = bid << BSH;
    int e0 = bstart[bid], e1 = bstart[bid + 1];
    __shared__ int cnt[256];
    __shared__ int ls[256];
    __shared__ int cur[256];
    cnt[t] = 0;
    __syncthreads();
    for (int e = e0 + t; e < e1; e += 256)
        atomicAdd(&cnt[pairs[e] >> 22], 1);
    __syncthreads();
    ls[t] = cnt[t];
    __syncthreads();
    for (int off = 1; off < 256; off <<= 1) {
        int x = (t >= off) ? ls[t - off] : 0;
        __syncthreads();
        ls[t] += x;
        __syncthreads();
    }
    int start = e0 + ((t == 0) ? 0 : ls[t - 1]);
    cur[t] = start;
    int node = n0 + t;
    if (node < N) {
        rowptr[node] = start;
        rowend[node] = start + cnt[t];
        dinv[node] = rsqrtf((float)cnt[t] + 1.0f);
    }
    __syncthreads();
    for (int e = e0 + t; e < e1; e += 256) {
        unsigned p = pairs[e];
        int r = atomicAdd(&cur[p >> 22], 1);
        colidx[r] = (int)(p & 0x3FFFFFu);
    }
}

// ================= network (bf16 hidden states) =================

// fused input + layer0: hl = bf16( dinv * (relu(x@Win+bin) @ W0) )
// wave per node; lane j owns output feature j; shuffle-broadcast of z.
__global__ __launch_bounds__(256) void k_gemm0(const float* __restrict__ x,
                                               const float* __restrict__ Win,
                                               const float* __restrict__ bin,
                                               const float* __restrict__ W,
                                               const float* __restrict__ dinv,
                                               unsigned short* __restrict__ hl, int N) {
    int j = threadIdx.x & 63;
    float w[64];
#pragma unroll
    for (int k = 0; k < 64; k++) w[k] = W[k * 64 + j];
    float wi[12];
#pragma unroll
    for (int k = 0; k < 12; k++) wi[k] = Win[k * 64 + j];
    float bj = bin[j];
    int wave = (blockIdx.x * 256 + threadIdx.x) >> 6;
    int nw = (gridDim.x * 256) >> 6;
    for (int node = wave; node < N; node += nw) {
        const float* xr = x + node * 12;
        float z = bj;
#pragma unroll
        for (int k = 0; k < 12; k++) z = fmaf(xr[k], wi[k], z);
        z = fmaxf(z, 0.0f);
        float acc = 0.0f;
#pragma unroll
        for (int k = 0; k < 64; k++) acc = fmaf(__shfl(z, k, 64), w[k], acc);
        hl[node * 64 + j] = (unsigned short)rne16(acc * dinv[node]);
    }
}

// fused BN-affine+relu + gemm (layers 1,2):
// hl = bf16( dinv * (relu(A*h+B) @ W) ), h read as raw bf16 agg output.
__global__ __launch_bounds__(256) void k_gemmn(const float* __restrict__ W,
                                               const float* __restrict__ ab,
                                               const float* __restrict__ dinv,
                                               const unsigned* __restrict__ h2,
                                               unsigned short* __restrict__ hl, int N) {
    int j = threadIdx.x & 63;
    float w[64];
#pragma unroll
    for (int k = 0; k < 64; k++) w[k] = W[k * 64 + j];
    float Aj = ab[j], Bj = ab[64 + j];
    int wave = (blockIdx.x * 256 + threadIdx.x) >> 6;
    int nw = (gridDim.x * 256) >> 6;
    for (int node = wave; node < N; node += nw) {
        unsigned u = h2[node * 32 + (j >> 1)];
        float h = (j & 1) ? bhi(u) : blo(u);
        float z = fmaxf(fmaf(Aj, h, Bj), 0.0f);
        float acc = 0.0f;
#pragma unroll
        for (int k = 0; k < 64; k++) acc = fmaf(__shfl(z, k, 64), w[k], acc);
        hl[node * 64 + j] = (unsigned short)rne16(acc * dinv[node]);
    }
}

// gather: out[d] = bf16( dinv[d]*(hl[d] + sum_s hl[s]) + b )
// PERSISTENT: grid-stride over dst rows; half-wave per row (R1 16-edge loop).
// BN stats accumulate in registers across rows; ONE end-of-block LDS reduce
// + 128 spread fp32 atomics per block (fire-and-forget, 262K total).
__global__ __launch_bounds__(256) void k_agg(const int* __restrict__ rowptr,
                                             const int* __restrict__ rowend,
                                             const int* __restrict__ colidx,
                                             const float* __restrict__ dinv,
                                             const unsigned* __restrict__ hl2,
                                             const float* __restrict__ b,
                                             unsigned* __restrict__ out2,
                                             float* __restrict__ ps, int N) {
    __shared__ float sms[8][64];
    __shared__ float smq[8][64];
    int t = threadIdx.x;
    int hw = t >> 5;            // half-wave id within block
    int lane = t & 31;
    int sub = lane >> 3;        // edge slot 0..3
    int q = lane & 7;           // uint4 chunk within the 128B row
    const uint4* H = (const uint4*)hl2;   // 8 x uint4 per 64-feat bf16 row
    int fb = q * 8;
    float bb0 = b[fb + 0], bb1 = b[fb + 1], bb2 = b[fb + 2], bb3 = b[fb + 3];
    float bb4 = b[fb + 4], bb5 = b[fb + 5], bb6 = b[fb + 6], bb7 = b[fb + 7];

    float s0 = 0.f, s1 = 0.f, s2 = 0.f, s3 = 0.f;
    float s4 = 0.f, s5 = 0.f, s6 = 0.f, s7 = 0.f;
    float q0 = 0.f, q1 = 0.f, q2 = 0.f, q3 = 0.f;
    float q4 = 0.f, q5 = 0.f, q6 = 0.f, q7 = 0.f;

    int nHW = gridDim.x * 8;
    for (int d = blockIdx.x * 8 + hw; d < N; d += nHW) {
        int e0 = rowptr[d], e1 = rowend[d];

        float a0 = 0.f, a1 = 0.f, a2 = 0.f, a3 = 0.f;
        float a4 = 0.f, a5 = 0.f, a6 = 0.f, a7 = 0.f;
        float b0 = 0.f, b1 = 0.f, b2 = 0.f, b3 = 0.f;
        float b4 = 0.f, b5 = 0.f, b6 = 0.f, b7 = 0.f;
        float c0 = 0.f, c1 = 0.f, c2 = 0.f, c3 = 0.f;
        float c4 = 0.f, c5 = 0.f, c6 = 0.f, c7 = 0.f;
        float g0 = 0.f, g1 = 0.f, g2 = 0.f, g3 = 0.f;
        float g4 = 0.f, g5 = 0.f, g6 = 0.f, g7 = 0.f;

        if (sub == 0) {        // self-loop term, added once
            uint4 su = H[d * 8 + q];
            a0 = blo(su.x); a1 = bhi(su.x);
            a2 = blo(su.y); a3 = bhi(su.y);
            a4 = blo(su.z); a5 = bhi(su.z);
            a6 = blo(su.w); a7 = bhi(su.w);
        }

        int e = e0 + sub;
        for (; e + 12 < e1; e += 16) {
            int i0 = colidx[e], i1 = colidx[e + 4];
            int i2 = colidx[e + 8], i3 = colidx[e + 12];
            uint4 u0 = H[i0 * 8 + q], u1 = H[i1 * 8 + q];
            uint4 u2 = H[i2 * 8 + q], u3 = H[i3 * 8 + q];
            a0 += blo(u0.x); a1 += bhi(u0.x); a2 += blo(u0.y); a3 += bhi(u0.y);
            a4 += blo(u0.z); a5 += bhi(u0.z); a6 += blo(u0.w); a7 += bhi(u0.w);
            b0 += blo(u1.x); b1 += bhi(u1.x); b2 += blo(u1.y); b3 += bhi(u1.y);
            b4 += blo(u1.z); b5 += bhi(u1.z); b6 += blo(u1.w); b7 += bhi(u1.w);
            c0 += blo(u2.x); c1 += bhi(u2.x); c2 += blo(u2.y); c3 += bhi(u2.y);
            c4 += blo(u2.z); c5 += bhi(u2.z); c6 += blo(u2.w); c7 += bhi(u2.w);
            g0 += blo(u3.x); g1 += bhi(u3.x); g2 += blo(u3.y); g3 += bhi(u3.y);
            g4 += blo(u3.z); g5 += bhi(u3.z); g6 += blo(u3.w); g7 += bhi(u3.w);
        }
        for (; e < e1; e += 4) {
            uint4 u = H[colidx[e] * 8 + q];
            a0 += blo(u.x); a1 += bhi(u.x); a2 += blo(u.y); a3 += bhi(u.y);
            a4 += blo(u.z); a5 += bhi(u.z); a6 += blo(u.w); a7 += bhi(u.w);
        }
        a0 += (b0 + c0) + g0; a1 += (b1 + c1) + g1;
        a2 += (b2 + c2) + g2; a3 += (b3 + c3) + g3;
        a4 += (b4 + c4) + g4; a5 += (b5 + c5) + g5;
        a6 += (b6 + c6) + g6; a7 += (b7 + c7) + g7;

        // butterfly across the 4 edge slots (stays inside the half-wave)
        a0 += __shfl_xor(a0, 8);  a0 += __shfl_xor(a0, 16);
        a1 += __shfl_xor(a1, 8);  a1 += __shfl_xor(a1, 16);
        a2 += __shfl_xor(a2, 8);  a2 += __shfl_xor(a2, 16);
        a3 += __shfl_xor(a3, 8);  a3 += __shfl_xor(a3, 16);
        a4 += __shfl_xor(a4, 8);  a4 += __shfl_xor(a4, 16);
        a5 += __shfl_xor(a5, 8);  a5 += __shfl_xor(a5, 16);
        a6 += __shfl_xor(a6, 8);  a6 += __shfl_xor(a6, 16);
        a7 += __shfl_xor(a7, 8);  a7 += __shfl_xor(a7, 16);

        if (sub == 0) {
            float dv = dinv[d];
            float o0 = fmaf(a0, dv, bb0);
            float o1 = fmaf(a1, dv, bb1);
            float o2 = fmaf(a2, dv, bb2);
            float o3 = fmaf(a3, dv, bb3);
            float o4 = fmaf(a4, dv, bb4);
            float o5 = fmaf(a5, dv, bb5);
            float o6 = fmaf(a6, dv, bb6);
            float o7 = fmaf(a7, dv, bb7);
            uint4 o;
            o.x = pk(o0, o1);
            o.y = pk(o2, o3);
            o.z = pk(o4, o5);
            o.w = pk(o6, o7);
            ((uint4*)out2)[d * 8 + q] = o;
            s0 += o0; q0 = fmaf(o0, o0, q0);
            s1 += o1; q1 = fmaf(o1, o1, q1);
            s2 += o2; q2 = fmaf(o2, o2, q2);
            s3 += o3; q3 = fmaf(o3, o3, q3);
            s4 += o4; q4 = fmaf(o4, o4, q4);
            s5 += o5; q5 = fmaf(o5, o5, q5);
            s6 += o6; q6 = fmaf(o6, o6, q6);
            s7 += o7; q7 = fmaf(o7, o7, q7);
        }
    }

    // one flush per block
    if (sub == 0) {
        sms[hw][fb + 0] = s0; sms[hw][fb + 1] = s1;
        sms[hw][fb + 2] = s2; sms[hw][fb + 3] = s3;
        sms[hw][fb + 4] = s4; sms[hw][fb + 5] = s5;
        sms[hw][fb + 6] = s6; sms[hw][fb + 7] = s7;
        smq[hw][fb + 0] = q0; smq[hw][fb + 1] = q1;
        smq[hw][fb + 2] = q2; smq[hw][fb + 3] = q3;
        smq[hw][fb + 4] = q4; smq[hw][fb + 5] = q5;
        smq[hw][fb + 6] = q6; smq[hw][fb + 7] = q7;
    }
    __syncthreads();
    if (t < 64) {
        float S = 0.f, Q = 0.f;
#pragma unroll
        for (int h = 0; h < 8; h++) {
            S += sms[h][t];
            Q += smq[h][t];
        }
        int col = blockIdx.x % PCOLS;
        atomicAdd(&ps[t * PCOLS + col], S);
        atomicAdd(&ps[(64 + t) * PCOLS + col], Q);
    }
}

// reduce spread partials -> BN affine A,B (ab[0..63]=A, ab[64..127]=B)
__global__ __launch_bounds__(64) void k_red(const float* __restrict__ ps,
                                            const float* __restrict__ gamma,
                                            const float* __restrict__ beta,
                                            float* __restrict__ ab, float invN) {
    int t = threadIdx.x;   // 64 threads, one per feature
    float S = 0.f, Q = 0.f;
    for (int i = 0; i < PCOLS; i++) {
        S += ps[t * PCOLS + i];
        Q += ps[(64 + t) * PCOLS + i];
    }
    float mu = S * invN;
    float var = fmaf(-mu, mu, Q * invN);
    float A = rsqrtf(var + EPSV) * gamma[t];
    ab[t] = A;
    ab[64 + t] = fmaf(-mu, A, beta[t]);
}

// classifier with BN2 affine folded into W1/b1 (no relu after BN2)
__global__ __launch_bounds__(256) void k_cls(const unsigned* __restrict__ h2,
                                             const float* __restrict__ ab,
                                             const float* __restrict__ W1,
                                             const float* __restrict__ b1,
                                             const float* __restrict__ W2,
                                             const float* __restrict__ b2,
                                             float* __restrict__ out, int N) {
    int lane = threadIdx.x & 63;
    int half = lane >> 5, jj = lane & 31;
    float w[64];
    float bj = b1[jj];
#pragma unroll
    for (int k = 0; k < 64; k++) {
        float w1 = W1[k * 32 + jj];
        w[k] = ab[k] * w1;
        bj = fmaf(ab[64 + k], w1, bj);
    }
    float w20 = W2[jj * 2 + 0], w21 = W2[jj * 2 + 1];
    float b20 = b2[0], b21 = b2[1];
    int wave = (blockIdx.x * 256 + threadIdx.x) >> 6;
    int nw = (gridDim.x * 256) >> 6;
    for (int base = wave * 2; base < N; base += nw * 2) {
        int node = base + half;
        int vnode = node < N ? node : 0;
        const uint4* row = (const uint4*)(h2 + vnode * 32);
        float acc = bj;
#pragma unroll
        for (int kk = 0; kk < 8; kk++) {
            uint4 u = row[kk];
            acc = fmaf(blo(u.x), w[8 * kk + 0], acc);
            acc = fmaf(bhi(u.x), w[8 * kk + 1], acc);
            acc = fmaf(blo(u.y), w[8 * kk + 2], acc);
            acc = fmaf(bhi(u.y), w[8 * kk + 3], acc);
            acc = fmaf(blo(u.z), w[8 * kk + 4], acc);
            acc = fmaf(bhi(u.z), w[8 * kk + 5], acc);
            acc = fmaf(blo(u.w), w[8 * kk + 6], acc);
            acc = fmaf(bhi(u.w), w[8 * kk + 7], acc);
        }
        float hv = fmaxf(acc, 0.0f);
        float t0 = hv * w20, t1 = hv * w21;
#pragma unroll
        for (int m = 1; m <= 16; m <<= 1) {
            t0 += __shfl_xor(t0, m, 64);
            t1 += __shfl_xor(t1, m, 64);
        }
        if (jj == 0 && node < N) {
            ((float2*)out)[node] = make_float2(t0 + b20, t1 + b21);
        }
    }
}

extern "C" void kernel_launch(void* const* d_in, const int* in_sizes, int n_in,
                              void* d_out, int out_size, void* d_ws, size_t ws_size,
                              hipStream_t stream) {
    const float* x     = (const float*)d_in[0];
    const int*   ei    = (const int*)d_in[1];
    const float* Win   = (const float*)d_in[2];
    const float* bin   = (const float*)d_in[3];
    const float* Wg    = (const float*)d_in[4];
    const float* bg    = (const float*)d_in[5];
    const float* gamma = (const float*)d_in[6];
    const float* beta  = (const float*)d_in[7];
    const float* W1    = (const float*)d_in[8];
    const float* b1    = (const float*)d_in[9];
    const float* W2    = (const float*)d_in[10];
    const float* b2    = (const float*)d_in[11];
    float* out = (float*)d_out;

    int N = in_sizes[0] / 12;
    int E = in_sizes[1] / 2;
    const int* src = ei;
    const int* dst = ei + E;
    float invN = 1.0f / (float)N;
    int NB = (N + BSZ - 1) >> BSH;

    char* ws = (char*)d_ws;
    size_t szhin = ((size_t)N * 64 * 2 + 255) / 256 * 256;  // bf16 hidden
    size_t szE4  = ((size_t)E * 4 + 255) / 256 * 256;
    size_t szN4  = ((size_t)N * 4 + 255) / 256 * 256;
    size_t szps  = (size_t)128 * PCOLS * 4;                 // one layer's partials

    size_t off = 0;
    unsigned* hin2     = (unsigned*)(ws + off); off += szhin;
    unsigned short* hl = (unsigned short*)(ws + off); off += szhin;
    int* colidx        = (int*)(ws + off); off += szE4;
    int* rowptr        = (int*)(ws + off); off += szN4;
    int* rowend        = (int*)(ws + off); off += szN4;
    float* dinv        = (float*)(ws + off); off += szN4;
    int* bcount        = (int*)(ws + off); off += 4096;     // memset start
    float* ps          = (float*)(ws + off); off += 3 * szps;
    size_t msz = 4096 + 3 * szps;                           // bcount + ps, one memset
    int* bstart        = (int*)(ws + off); off += 8192;     // 1025 ints
    int* gcur          = (int*)(ws + off); off += 4096;
    float* ab          = (float*)(ws + off); off += 512;

    // packed pairs (4B) alias [hin2 | hl] — consumed by k_build before k_gemm0
    unsigned* pairs = (unsigned*)ws;
    size_t need = off;
    if (2 * szhin < (size_t)E * 4) {
        pairs = (unsigned*)(ws + off);
        need += (size_t)E * 4;
    }
    if (ws_size < need || NB > 1024 || N >= (1 << 22)) return;  // loud failure

    hipMemsetAsync(bcount, 0, msz, stream);

    int EB = (E + 4095) / 4096;
    k_hist<<<EB, 256, 0, stream>>>(dst, bcount, E);
    k_bscan<<<1, 256, 0, stream>>>(bcount, bstart, gcur, NB);
    k_split<<<EB, 256, 0, stream>>>(src, dst, gcur, pairs, E);
    k_build<<<NB, 256, 0, stream>>>(pairs, bstart, rowptr, rowend, dinv, colidx, N);

    int AB = (N + 7) / 8;
    if (AB > 2048) AB = 2048;   // persistent agg grid
    for (int i = 0; i < 3; i++) {
        if (i == 0)
            k_gemm0<<<1024, 256, 0, stream>>>(x, Win, bin, Wg, dinv, hl, N);
        else
            k_gemmn<<<1024, 256, 0, stream>>>(Wg + i * 64 * 64, ab, dinv, hin2,
                                              hl, N);
        k_agg<<<AB, 256, 0, stream>>>(rowptr, rowend, colidx, dinv,
                                      (const unsigned*)hl, bg + i * 64, hin2,
                                      ps + (size_t)i * 128 * PCOLS, N);
        k_red<<<1, 64, 0, stream>>>(ps + (size_t)i * 128 * PCOLS, gamma + i * 64,
                                    beta + i * 64, ab, invN);
    }
    k_cls<<<1024, 256, 0, stream>>>(hin2, ab, W1, b1, W2, b2, out, N);
}

// Round 7
// 512.337 us; speedup vs baseline: 1.4850x; 1.2583x over previous
//
#include <hip/hip_runtime.h>

#define EPSV 1e-5f
#define BSH 8           // bucket shift: 256 nodes per bucket
#define BSZ 256
#define PCOLS 104       // stats partial spread columns

// bf16x2 helpers (bf16 = top 16 bits of fp32; element 2f = low half)
__device__ inline float blo(unsigned u) { return __uint_as_float(u << 16); }
__device__ inline float bhi(unsigned u) { return __uint_as_float(u & 0xFFFF0000u); }
__device__ inline unsigned rne16(float v) {
    unsigned u = __float_as_uint(v);
    return (u + 0x7FFFu + ((u >> 16) & 1u)) >> 16;
}
__device__ inline unsigned pk(float lo, float hi) {
    return (rne16(hi) << 16) | rne16(lo);
}

// ================= CSR build: multisplit, 256-node buckets, 4B pairs =====

__global__ __launch_bounds__(256) void k_hist(const int* __restrict__ dst,
                                              int* __restrict__ bcount, int E) {
    __shared__ int hist[1024];
    int t = threadIdx.x;
#pragma unroll
    for (int i = 0; i < 4; i++) hist[t + 256 * i] = 0;
    __syncthreads();
    int e0 = blockIdx.x * 4096;
#pragma unroll
    for (int r = 0; r < 16; r++) {
        int e = e0 + r * 256 + t;
        if (e < E) atomicAdd(&hist[dst[e] >> BSH], 1);
    }
    __syncthreads();
#pragma unroll
    for (int i = 0; i < 4; i++) {
        int bk = t + 256 * i;
        int h = hist[bk];
        if (h) atomicAdd(&bcount[bk], h);
    }
}

__global__ __launch_bounds__(256) void k_bscan(const int* __restrict__ bcount,
                                               int* __restrict__ bstart,
                                               int* __restrict__ gcur, int NB) {
    int t = threadIdx.x;
    int base = t * 4;
    int c[4], s = 0;
#pragma unroll
    for (int i = 0; i < 4; i++) {
        c[i] = (base + i < NB) ? bcount[base + i] : 0;
        s += c[i];
    }
    __shared__ int ls[256];
    ls[t] = s;
    __syncthreads();
    for (int off = 1; off < 256; off <<= 1) {
        int x = (t >= off) ? ls[t - off] : 0;
        __syncthreads();
        ls[t] += x;
        __syncthreads();
    }
    int run = (t == 0) ? 0 : ls[t - 1];
#pragma unroll
    for (int i = 0; i < 4; i++) {
        bstart[base + i] = run;
        gcur[base + i] = run;
        run += c[i];
    }
    if (t == 255) bstart[1024] = ls[255];
}

// pack: (dst_local << 22) | src   (src < 2^22, dst_local < 256)
__global__ __launch_bounds__(256) void k_split(const int* __restrict__ src,
                                               const int* __restrict__ dst,
                                               int* __restrict__ gcur,
                                               unsigned* __restrict__ pairs, int E) {
    __shared__ int hist[1024];   // reused as rank counters in pass 2
    __shared__ int gb[1024];
    int t = threadIdx.x;
    int e0 = blockIdx.x * 4096;
    int sreg[16], dreg[16];
#pragma unroll
    for (int i = 0; i < 4; i++) hist[t + 256 * i] = 0;
    __syncthreads();
#pragma unroll
    for (int r = 0; r < 16; r++) {
        int e = e0 + r * 256 + t;
        if (e < E) {
            sreg[r] = src[e];
            dreg[r] = dst[e];
            atomicAdd(&hist[dreg[r] >> BSH], 1);
        } else {
            dreg[r] = -1;
        }
    }
    __syncthreads();
#pragma unroll
    for (int i = 0; i < 4; i++) {
        int bk = t + 256 * i;
        int h = hist[bk];
        gb[bk] = h ? atomicAdd(&gcur[bk], h) : 0;
    }
    __syncthreads();
#pragma unroll
    for (int i = 0; i < 4; i++) hist[t + 256 * i] = 0;
    __syncthreads();
#pragma unroll
    for (int r = 0; r < 16; r++) {
        if (dreg[r] >= 0) {
            int bk = dreg[r] >> BSH;
            int rk = atomicAdd(&hist[bk], 1);
            pairs[gb[bk] + rk] = ((unsigned)(dreg[r] & (BSZ - 1)) << 22) |
                                 (unsigned)sreg[r];
        }
    }
}

// one block per 256-node bucket
__global__ __launch_bounds__(256) void k_build(const unsigned* __restrict__ pairs,
                                               const int* __restrict__ bstart,
                                               int* __restrict__ rowptr,
                                               int* __restrict__ rowend,
                                               float* __restrict__ dinv,
                                               int* __restrict__ colidx, int N) {
    int bid = blockIdx.x, t = threadIdx.x;
    int n0 = bid << BSH;
    int e0 = bstart[bid], e1 = bstart[bid + 1];
    __shared__ int cnt[256];
    __shared__ int ls[256];
    __shared__ int cur[256];
    cnt[t] = 0;
    __syncthreads();
    for (int e = e0 + t; e < e1; e += 256)
        atomicAdd(&cnt[pairs[e] >> 22], 1);
    __syncthreads();
    ls[t] = cnt[t];
    __syncthreads();
    for (int off = 1; off < 256; off <<= 1) {
        int x = (t >= off) ? ls[t - off] : 0;
        __syncthreads();
        ls[t] += x;
        __syncthreads();
    }
    int start = e0 + ((t == 0) ? 0 : ls[t - 1]);
    cur[t] = start;
    int node = n0 + t;
    if (node < N) {
        rowptr[node] = start;
        rowend[node] = start + cnt[t];
        dinv[node] = rsqrtf((float)cnt[t] + 1.0f);
    }
    __syncthreads();
    for (int e = e0 + t; e < e1; e += 256) {
        unsigned p = pairs[e];
        int r = atomicAdd(&cur[p >> 22], 1);
        colidx[r] = (int)(p & 0x3FFFFFu);
    }
}

// ================= network (bf16 hidden states) =================

// fused input + layer0: hl = bf16( dinv * (relu(x@Win+bin) @ W0) )
// wave per node; lane j computes z_j; broadcast via per-wave LDS slice
// (no __syncthreads needed: same-wave DS ops are ordered; one lgkmcnt wait).
__global__ __launch_bounds__(256) void k_gemm0(const float* __restrict__ x,
                                               const float* __restrict__ Win,
                                               const float* __restrict__ bin,
                                               const float* __restrict__ W,
                                               const float* __restrict__ dinv,
                                               unsigned short* __restrict__ hl, int N) {
    __shared__ float zbuf[4][64];
    int wv = threadIdx.x >> 6;
    int j = threadIdx.x & 63;
    float w[64];
#pragma unroll
    for (int k = 0; k < 64; k++) w[k] = W[k * 64 + j];
    float wi[12];
#pragma unroll
    for (int k = 0; k < 12; k++) wi[k] = Win[k * 64 + j];
    float bj = bin[j];
    const float4* zr = (const float4*)&zbuf[wv][0];
    int wave = (blockIdx.x * 256 + threadIdx.x) >> 6;
    int nw = (gridDim.x * 256) >> 6;
    for (int node = wave; node < N; node += nw) {
        const float* xr = x + node * 12;
        float z = bj;
#pragma unroll
        for (int k = 0; k < 12; k++) z = fmaf(xr[k], wi[k], z);
        zbuf[wv][j] = fmaxf(z, 0.0f);
        asm volatile("s_waitcnt lgkmcnt(0)" ::: "memory");
        float acc = 0.0f;
#pragma unroll
        for (int kk = 0; kk < 16; kk++) {
            float4 z4 = zr[kk];
            acc = fmaf(z4.x, w[4 * kk + 0], acc);
            acc = fmaf(z4.y, w[4 * kk + 1], acc);
            acc = fmaf(z4.z, w[4 * kk + 2], acc);
            acc = fmaf(z4.w, w[4 * kk + 3], acc);
        }
        hl[node * 64 + j] = (unsigned short)rne16(acc * dinv[node]);
    }
}

// fused BN-affine+relu + gemm (layers 1,2):
// hl = bf16( dinv * (relu(A*h+B) @ W) ), broadcast via per-wave LDS slice.
__global__ __launch_bounds__(256) void k_gemmn(const float* __restrict__ W,
                                               const float* __restrict__ ab,
                                               const float* __restrict__ dinv,
                                               const unsigned* __restrict__ h2,
                                               unsigned short* __restrict__ hl, int N) {
    __shared__ float zbuf[4][64];
    int wv = threadIdx.x >> 6;
    int j = threadIdx.x & 63;
    float w[64];
#pragma unroll
    for (int k = 0; k < 64; k++) w[k] = W[k * 64 + j];
    float Aj = ab[j], Bj = ab[64 + j];
    const float4* zr = (const float4*)&zbuf[wv][0];
    int wave = (blockIdx.x * 256 + threadIdx.x) >> 6;
    int nw = (gridDim.x * 256) >> 6;
    for (int node = wave; node < N; node += nw) {
        unsigned u = h2[node * 32 + (j >> 1)];
        float h = (j & 1) ? bhi(u) : blo(u);
        zbuf[wv][j] = fmaxf(fmaf(Aj, h, Bj), 0.0f);
        asm volatile("s_waitcnt lgkmcnt(0)" ::: "memory");
        float acc = 0.0f;
#pragma unroll
        for (int kk = 0; kk < 16; kk++) {
            float4 z4 = zr[kk];
            acc = fmaf(z4.x, w[4 * kk + 0], acc);
            acc = fmaf(z4.y, w[4 * kk + 1], acc);
            acc = fmaf(z4.z, w[4 * kk + 2], acc);
            acc = fmaf(z4.w, w[4 * kk + 3], acc);
        }
        hl[node * 64 + j] = (unsigned short)rne16(acc * dinv[node]);
    }
}

// gather: out[d] = bf16( dinv[d]*(hl[d] + sum_s hl[s]) + b )
// PERSISTENT: grid-stride over dst rows; half-wave per row (R1 16-edge loop).
// BN stats accumulate in registers across rows; ONE end-of-block LDS reduce
// + 128 spread fp32 atomics per block (fire-and-forget, 262K total).
__global__ __launch_bounds__(256) void k_agg(const int* __restrict__ rowptr,
                                             const int* __restrict__ rowend,
                                             const int* __restrict__ colidx,
                                             const float* __restrict__ dinv,
                                             const unsigned* __restrict__ hl2,
                                             const float* __restrict__ b,
                                             unsigned* __restrict__ out2,
                                             float* __restrict__ ps, int N) {
    __shared__ float sms[8][64];
    __shared__ float smq[8][64];
    int t = threadIdx.x;
    int hw = t >> 5;            // half-wave id within block
    int lane = t & 31;
    int sub = lane >> 3;        // edge slot 0..3
    int q = lane & 7;           // uint4 chunk within the 128B row
    const uint4* H = (const uint4*)hl2;   // 8 x uint4 per 64-feat bf16 row
    int fb = q * 8;
    float bb0 = b[fb + 0], bb1 = b[fb + 1], bb2 = b[fb + 2], bb3 = b[fb + 3];
    float bb4 = b[fb + 4], bb5 = b[fb + 5], bb6 = b[fb + 6], bb7 = b[fb + 7];

    float s0 = 0.f, s1 = 0.f, s2 = 0.f, s3 = 0.f;
    float s4 = 0.f, s5 = 0.f, s6 = 0.f, s7 = 0.f;
    float q0 = 0.f, q1 = 0.f, q2 = 0.f, q3 = 0.f;
    float q4 = 0.f, q5 = 0.f, q6 = 0.f, q7 = 0.f;

    int nHW = gridDim.x * 8;
    for (int d = blockIdx.x * 8 + hw; d < N; d += nHW) {
        int e0 = rowptr[d], e1 = rowend[d];

        float a0 = 0.f, a1 = 0.f, a2 = 0.f, a3 = 0.f;
        float a4 = 0.f, a5 = 0.f, a6 = 0.f, a7 = 0.f;
        float b0 = 0.f, b1 = 0.f, b2 = 0.f, b3 = 0.f;
        float b4 = 0.f, b5 = 0.f, b6 = 0.f, b7 = 0.f;
        float c0 = 0.f, c1 = 0.f, c2 = 0.f, c3 = 0.f;
        float c4 = 0.f, c5 = 0.f, c6 = 0.f, c7 = 0.f;
        float g0 = 0.f, g1 = 0.f, g2 = 0.f, g3 = 0.f;
        float g4 = 0.f, g5 = 0.f, g6 = 0.f, g7 = 0.f;

        if (sub == 0) {        // self-loop term, added once
            uint4 su = H[d * 8 + q];
            a0 = blo(su.x); a1 = bhi(su.x);
            a2 = blo(su.y); a3 = bhi(su.y);
            a4 = blo(su.z); a5 = bhi(su.z);
            a6 = blo(su.w); a7 = bhi(su.w);
        }

        int e = e0 + sub;
        for (; e + 12 < e1; e += 16) {
            int i0 = colidx[e], i1 = colidx[e + 4];
            int i2 = colidx[e + 8], i3 = colidx[e + 12];
            uint4 u0 = H[i0 * 8 + q], u1 = H[i1 * 8 + q];
            uint4 u2 = H[i2 * 8 + q], u3 = H[i3 * 8 + q];
            a0 += blo(u0.x); a1 += bhi(u0.x); a2 += blo(u0.y); a3 += bhi(u0.y);
            a4 += blo(u0.z); a5 += bhi(u0.z); a6 += blo(u0.w); a7 += bhi(u0.w);
            b0 += blo(u1.x); b1 += bhi(u1.x); b2 += blo(u1.y); b3 += bhi(u1.y);
            b4 += blo(u1.z); b5 += bhi(u1.z); b6 += blo(u1.w); b7 += bhi(u1.w);
            c0 += blo(u2.x); c1 += bhi(u2.x); c2 += blo(u2.y); c3 += bhi(u2.y);
            c4 += blo(u2.z); c5 += bhi(u2.z); c6 += blo(u2.w); c7 += bhi(u2.w);
            g0 += blo(u3.x); g1 += bhi(u3.x); g2 += blo(u3.y); g3 += bhi(u3.y);
            g4 += blo(u3.z); g5 += bhi(u3.z); g6 += blo(u3.w); g7 += bhi(u3.w);
        }
        for (; e < e1; e += 4) {
            uint4 u = H[colidx[e] * 8 + q];
            a0 += blo(u.x); a1 += bhi(u.x); a2 += blo(u.y); a3 += bhi(u.y);
            a4 += blo(u.z); a5 += bhi(u.z); a6 += blo(u.w); a7 += bhi(u.w);
        }
        a0 += (b0 + c0) + g0; a1 += (b1 + c1) + g1;
        a2 += (b2 + c2) + g2; a3 += (b3 + c3) + g3;
        a4 += (b4 + c4) + g4; a5 += (b5 + c5) + g5;
        a6 += (b6 + c6) + g6; a7 += (b7 + c7) + g7;

        // butterfly across the 4 edge slots (stays inside the half-wave)
        a0 += __shfl_xor(a0, 8);  a0 += __shfl_xor(a0, 16);
        a1 += __shfl_xor(a1, 8);  a1 += __shfl_xor(a1, 16);
        a2 += __shfl_xor(a2, 8);  a2 += __shfl_xor(a2, 16);
        a3 += __shfl_xor(a3, 8);  a3 += __shfl_xor(a3, 16);
        a4 += __shfl_xor(a4, 8);  a4 += __shfl_xor(a4, 16);
        a5 += __shfl_xor(a5, 8);  a5 += __shfl_xor(a5, 16);
        a6 += __shfl_xor(a6, 8);  a6 += __shfl_xor(a6, 16);
        a7 += __shfl_xor(a7, 8);  a7 += __shfl_xor(a7, 16);

        if (sub == 0) {
            float dv = dinv[d];
            float o0 = fmaf(a0, dv, bb0);
            float o1 = fmaf(a1, dv, bb1);
            float o2 = fmaf(a2, dv, bb2);
            float o3 = fmaf(a3, dv, bb3);
            float o4 = fmaf(a4, dv, bb4);
            float o5 = fmaf(a5, dv, bb5);
            float o6 = fmaf(a6, dv, bb6);
            float o7 = fmaf(a7, dv, bb7);
            uint4 o;
            o.x = pk(o0, o1);
            o.y = pk(o2, o3);
            o.z = pk(o4, o5);
            o.w = pk(o6, o7);
            ((uint4*)out2)[d * 8 + q] = o;
            s0 += o0; q0 = fmaf(o0, o0, q0);
            s1 += o1; q1 = fmaf(o1, o1, q1);
            s2 += o2; q2 = fmaf(o2, o2, q2);
            s3 += o3; q3 = fmaf(o3, o3, q3);
            s4 += o4; q4 = fmaf(o4, o4, q4);
            s5 += o5; q5 = fmaf(o5, o5, q5);
            s6 += o6; q6 = fmaf(o6, o6, q6);
            s7 += o7; q7 = fmaf(o7, o7, q7);
        }
    }

    // one flush per block
    if (sub == 0) {
        sms[hw][fb + 0] = s0; sms[hw][fb + 1] = s1;
        sms[hw][fb + 2] = s2; sms[hw][fb + 3] = s3;
        sms[hw][fb + 4] = s4; sms[hw][fb + 5] = s5;
        sms[hw][fb + 6] = s6; sms[hw][fb + 7] = s7;
        smq[hw][fb + 0] = q0; smq[hw][fb + 1] = q1;
        smq[hw][fb + 2] = q2; smq[hw][fb + 3] = q3;
        smq[hw][fb + 4] = q4; smq[hw][fb + 5] = q5;
        smq[hw][fb + 6] = q6; smq[hw][fb + 7] = q7;
    }
    __syncthreads();
    if (t < 64) {
        float S = 0.f, Q = 0.f;
#pragma unroll
        for (int h = 0; h < 8; h++) {
            S += sms[h][t];
            Q += smq[h][t];
        }
        int col = blockIdx.x % PCOLS;
        atomicAdd(&ps[t * PCOLS + col], S);
        atomicAdd(&ps[(64 + t) * PCOLS + col], Q);
    }
}

// reduce spread partials -> BN affine A,B (ab[0..63]=A, ab[64..127]=B)
__global__ __launch_bounds__(64) void k_red(const float* __restrict__ ps,
                                            const float* __restrict__ gamma,
                                            const float* __restrict__ beta,
                                            float* __restrict__ ab, float invN) {
    int t = threadIdx.x;   // 64 threads, one per feature
    float S = 0.f, Q = 0.f;
    for (int i = 0; i < PCOLS; i++) {
        S += ps[t * PCOLS + i];
        Q += ps[(64 + t) * PCOLS + i];
    }
    float mu = S * invN;
    float var = fmaf(-mu, mu, Q * invN);
    float A = rsqrtf(var + EPSV) * gamma[t];
    ab[t] = A;
    ab[64 + t] = fmaf(-mu, A, beta[t]);
}

// classifier with BN2 affine folded into W1/b1 (no relu after BN2)
__global__ __launch_bounds__(256) void k_cls(const unsigned* __restrict__ h2,
                                             const float* __restrict__ ab,
                                             const float* __restrict__ W1,
                                             const float* __restrict__ b1,
                                             const float* __restrict__ W2,
                                             const float* __restrict__ b2,
                                             float* __restrict__ out, int N) {
    int lane = threadIdx.x & 63;
    int half = lane >> 5, jj = lane & 31;
    float w[64];
    float bj = b1[jj];
#pragma unroll
    for (int k = 0; k < 64; k++) {
        float w1 = W1[k * 32 + jj];
        w[k] = ab[k] * w1;
        bj = fmaf(ab[64 + k], w1, bj);
    }
    float w20 = W2[jj * 2 + 0], w21 = W2[jj * 2 + 1];
    float b20 = b2[0], b21 = b2[1];
    int wave = (blockIdx.x * 256 + threadIdx.x) >> 6;
    int nw = (gridDim.x * 256) >> 6;
    for (int base = wave * 2; base < N; base += nw * 2) {
        int node = base + half;
        int vnode = node < N ? node : 0;
        const uint4* row = (const uint4*)(h2 + vnode * 32);
        float acc = bj;
#pragma unroll
        for (int kk = 0; kk < 8; kk++) {
            uint4 u = row[kk];
            acc = fmaf(blo(u.x), w[8 * kk + 0], acc);
            acc = fmaf(bhi(u.x), w[8 * kk + 1], acc);
            acc = fmaf(blo(u.y), w[8 * kk + 2], acc);
            acc = fmaf(bhi(u.y), w[8 * kk + 3], acc);
            acc = fmaf(blo(u.z), w[8 * kk + 4], acc);
            acc = fmaf(bhi(u.z), w[8 * kk + 5], acc);
            acc = fmaf(blo(u.w), w[8 * kk + 6], acc);
            acc = fmaf(bhi(u.w), w[8 * kk + 7], acc);
        }
        float hv = fmaxf(acc, 0.0f);
        float t0 = hv * w20, t1 = hv * w21;
#pragma unroll
        for (int m = 1; m <= 16; m <<= 1) {
            t0 += __shfl_xor(t0, m, 64);
            t1 += __shfl_xor(t1, m, 64);
        }
        if (jj == 0 && node < N) {
            ((float2*)out)[node] = make_float2(t0 + b20, t1 + b21);
        }
    }
}

extern "C" void kernel_launch(void* const* d_in, const int* in_sizes, int n_in,
                              void* d_out, int out_size, void* d_ws, size_t ws_size,
                              hipStream_t stream) {
    const float* x     = (const float*)d_in[0];
    const int*   ei    = (const int*)d_in[1];
    const float* Win   = (const float*)d_in[2];
    const float* bin   = (const float*)d_in[3];
    const float* Wg    = (const float*)d_in[4];
    const float* bg    = (const float*)d_in[5];
    const float* gamma = (const float*)d_in[6];
    const float* beta  = (const float*)d_in[7];
    const float* W1    = (const float*)d_in[8];
    const float* b1    = (const float*)d_in[9];
    const float* W2    = (const float*)d_in[10];
    const float* b2    = (const float*)d_in[11];
    float* out = (float*)d_out;

    int N = in_sizes[0] / 12;
    int E = in_sizes[1] / 2;
    const int* src = ei;
    const int* dst = ei + E;
    float invN = 1.0f / (float)N;
    int NB = (N + BSZ - 1) >> BSH;

    char* ws = (char*)d_ws;
    size_t szhin = ((size_t)N * 64 * 2 + 255) / 256 * 256;  // bf16 hidden
    size_t szE4  = ((size_t)E * 4 + 255) / 256 * 256;
    size_t szN4  = ((size_t)N * 4 + 255) / 256 * 256;
    size_t szps  = (size_t)128 * PCOLS * 4;                 // one layer's partials

    size_t off = 0;
    unsigned* hin2     = (unsigned*)(ws + off); off += szhin;
    unsigned short* hl = (unsigned short*)(ws + off); off += szhin;
    int* colidx        = (int*)(ws + off); off += szE4;
    int* rowptr        = (int*)(ws + off); off += szN4;
    int* rowend        = (int*)(ws + off); off += szN4;
    float* dinv        = (float*)(ws + off); off += szN4;
    int* bcount        = (int*)(ws + off); off += 4096;     // memset start
    float* ps          = (float*)(ws + off); off += 3 * szps;
    size_t msz = 4096 + 3 * szps;                           // bcount + ps, one memset
    int* bstart        = (int*)(ws + off); off += 8192;     // 1025 ints
    int* gcur          = (int*)(ws + off); off += 4096;
    float* ab          = (float*)(ws + off); off += 512;

    // packed pairs (4B) alias [hin2 | hl] — consumed by k_build before k_gemm0
    unsigned* pairs = (unsigned*)ws;
    size_t need = off;
    if (2 * szhin < (size_t)E * 4) {
        pairs = (unsigned*)(ws + off);
        need += (size_t)E * 4;
    }
    if (ws_size < need || NB > 1024 || N >= (1 << 22)) return;  // loud failure

    hipMemsetAsync(bcount, 0, msz, stream);

    int EB = (E + 4095) / 4096;
    k_hist<<<EB, 256, 0, stream>>>(dst, bcount, E);
    k_bscan<<<1, 256, 0, stream>>>(bcount, bstart, gcur, NB);
    k_split<<<EB, 256, 0, stream>>>(src, dst, gcur, pairs, E);
    k_build<<<NB, 256, 0, stream>>>(pairs, bstart, rowptr, rowend, dinv, colidx, N);

    int AB = (N + 7) / 8;
    if (AB > 2048) AB = 2048;   // persistent agg grid
    for (int i = 0; i < 3; i++) {
        if (i == 0)
            k_gemm0<<<2048, 256, 0, stream>>>(x, Win, bin, Wg, dinv, hl, N);
        else
            k_gemmn<<<2048, 256, 0, stream>>>(Wg + i * 64 * 64, ab, dinv, hin2,
                                              hl, N);
        k_agg<<<AB, 256, 0, stream>>>(rowptr, rowend, colidx, dinv,
                                      (const unsigned*)hl, bg + i * 64, hin2,
                                      ps + (size_t)i * 128 * PCOLS, N);
        k_red<<<1, 64, 0, stream>>>(ps + (size_t)i * 128 * PCOLS, gamma + i * 64,
                                    beta + i * 64, ab, invN);
    }
    k_cls<<<1024, 256, 0, stream>>>(hin2, ab, W1, b1, W2, b2, out, N);
}